// Round 4
// baseline (441.031 us; speedup 1.0000x reference)
//
#include <hip/hip_runtime.h>
#include <hip/hip_bf16.h>

// Problem constants
#define B_ 16
#define T_ 1024
#define D_ 1024

using frag8 = __attribute__((ext_vector_type(8))) short;   // 8 bf16 (4 VGPRs)
using f32x4 = __attribute__((ext_vector_type(4))) float;   // 4 fp32 acc

__device__ inline unsigned short f2bf(float f) {
    union { float f; unsigned u; } v; v.f = f;
    unsigned r = v.u + 0x7FFF + ((v.u >> 16) & 1);   // round-nearest-even
    return (unsigned short)(r >> 16);
}

// ---------------------------------------------------------------------------
// K0a: x fp32 -> bf16  (16M elems, float4 in / ushort4 out, pure BW)
// ---------------------------------------------------------------------------
__global__ __launch_bounds__(256)
void cvt_x(const float* __restrict__ x, unsigned short* __restrict__ xb) {
    int i = blockIdx.x * 256 + threadIdx.x;          // group of 4 elems
    float4 v = ((const float4*)x)[i];
    ushort4 o;
    o.x = f2bf(v.x); o.y = f2bf(v.y); o.z = f2bf(v.z); o.w = f2bf(v.w);
    ((ushort4*)xb)[i] = o;
}

// ---------------------------------------------------------------------------
// K0b: W fp32 [k][n] -> bf16 TRANSPOSED wt[z][n][k]  (64x64 LDS tile transpose)
// grid (16,16,3) block 256
// ---------------------------------------------------------------------------
__global__ __launch_bounds__(256)
void cvt_wt(const float* __restrict__ Wq, const float* __restrict__ Wk,
            const float* __restrict__ Wv, unsigned short* __restrict__ wt) {
    __shared__ unsigned short t[64][65];
    const float* W = (blockIdx.z == 0) ? Wq : (blockIdx.z == 1 ? Wk : Wv);
    const int n0 = blockIdx.x * 64, k0 = blockIdx.y * 64;
    const int tn = threadIdx.x & 63;   // coalesced over n
    const int tk = threadIdx.x >> 6;   // 0..3
#pragma unroll
    for (int it = 0; it < 16; ++it) {
        int k = tk + it * 4;
        t[tn][k] = f2bf(W[(size_t)(k0 + k) * D_ + n0 + tn]);
    }
    __syncthreads();
    const int wk = threadIdx.x & 63;   // coalesced over k
    const int wn = threadIdx.x >> 6;
#pragma unroll
    for (int it = 0; it < 16; ++it) {
        int n = wn + it * 4;
        wt[((size_t)blockIdx.z << 20) + (size_t)(n0 + n) * D_ + k0 + wk] = t[n][wk];
    }
}

// ---------------------------------------------------------------------------
// K0c: Wfc fp32 (1M flat, = [q][d] row-major) -> bf16 (2 MB, L2-resident)
// grid 1024 x 256
// ---------------------------------------------------------------------------
__global__ __launch_bounds__(256)
void cvt_wfc(const float* __restrict__ wfc, unsigned short* __restrict__ wb) {
    int i = blockIdx.x * 256 + threadIdx.x;
    float4 v = ((const float4*)wfc)[i];
    ushort4 o;
    o.x = f2bf(v.x); o.y = f2bf(v.y); o.z = f2bf(v.z); o.w = f2bf(v.w);
    ((ushort4*)wb)[i] = o;
}

// ---------------------------------------------------------------------------
// K1: fused Q/K/V projection, m97-style staging.
// NEW SWIZZLE: each XCD (l&7) owns 16 m-blocks (4 MB of x = L2-resident) and
// iterates all 24 (z,nblk) W-slabs; 3 same-x slabs innermost for L1/L2 reuse.
// grid: (8, 128, 3) linear = x + 8*y + 1024*z.   block: 256
// ---------------------------------------------------------------------------
__global__ __launch_bounds__(256)
void qkv_gemm3(const unsigned short* __restrict__ xb,
               const unsigned short* __restrict__ wt,
               const float* __restrict__ bq, const float* __restrict__ bk,
               const float* __restrict__ bv,
               unsigned short* __restrict__ qb,
               unsigned short* __restrict__ kb,
               unsigned short* __restrict__ vb) {
    __shared__ __align__(16) unsigned short As[128 * 32];
    __shared__ __align__(16) unsigned short Bs[128 * 32];

    const int l    = blockIdx.x + 8 * blockIdx.y + 1024 * blockIdx.z;
    const int xcd  = l & 7;
    const int idx  = l >> 3;            // 0..383
    const int sgrp = idx / 48;          // slab group 0..7
    const int rem  = idx - sgrp * 48;
    const int mgrp = rem / 3;           // 0..15
    const int s_in = rem - mgrp * 3;    // 0..2
    const int slab = sgrp * 3 + s_in;   // 0..23
    const int mblk = xcd * 16 + mgrp;   // 0..127
    const int z    = slab >> 3;
    const int nblk = slab & 7;

    const int m0 = mblk * 128, n0 = nblk * 128;
    const unsigned short* Wz = wt + ((size_t)z << 20);
    const float* bias  = (z == 0) ? bq : (z == 1 ? bk : bv);
    unsigned short* out = (z == 0) ? qb : (z == 1 ? kb : vb);

    const int tid = threadIdx.x, lane = tid & 63, wave = tid >> 6;
    const int wm = (wave >> 1) * 64, wn = (wave & 1) * 64;

    f32x4 acc[4][4];
#pragma unroll
    for (int i = 0; i < 4; i++)
#pragma unroll
        for (int j = 0; j < 4; j++) acc[i][j] = (f32x4){0.f, 0.f, 0.f, 0.f};

    const int srow = lane >> 2;          // row within 16-row group
    const int sk   = (lane & 3) * 8;     // k elem offset
    const int fr = lane & 15, fk = (lane >> 4) * 8;

    for (int k0 = 0; k0 < D_; k0 += 32) {
#pragma unroll
        for (int it = 0; it < 2; ++it) {
            const int rb = wave * 2 + it;           // 16-row group 0..7
            const int r  = rb * 16 + srow;
            __builtin_amdgcn_global_load_lds(
                (const __attribute__((address_space(1))) unsigned int*)
                    (xb + (size_t)(m0 + r) * D_ + k0 + sk),
                (__attribute__((address_space(3))) unsigned int*)(As + rb * 512),
                16, 0, 0);
            __builtin_amdgcn_global_load_lds(
                (const __attribute__((address_space(1))) unsigned int*)
                    (Wz + (size_t)(n0 + r) * D_ + k0 + sk),
                (__attribute__((address_space(3))) unsigned int*)(Bs + rb * 512),
                16, 0, 0);
        }
        __syncthreads();

        frag8 af[4], bff[4];
#pragma unroll
        for (int t = 0; t < 4; ++t)
            af[t] = *(const frag8*)&As[(wm + t * 16 + fr) * 32 + fk];
#pragma unroll
        for (int t = 0; t < 4; ++t)
            bff[t] = *(const frag8*)&Bs[(wn + t * 16 + fr) * 32 + fk];
#pragma unroll
        for (int i = 0; i < 4; i++)
#pragma unroll
            for (int j = 0; j < 4; j++)
                acc[i][j] = __builtin_amdgcn_mfma_f32_16x16x32_bf16(
                    af[i], bff[j], acc[i][j], 0, 0, 0);
        __syncthreads();
    }

    const int col   = lane & 15;
    const int rbase = (lane >> 4) * 4;
#pragma unroll
    for (int i = 0; i < 4; i++) {
#pragma unroll
        for (int j = 0; j < 4; j++) {
            int gn = n0 + wn + j * 16 + col;
            float bb = bias[gn];
#pragma unroll
            for (int r = 0; r < 4; r++) {
                int gm = m0 + wm + i * 16 + rbase + r;
                out[(size_t)gm * D_ + gn] = f2bf(acc[i][j][r] + bb);
            }
        }
    }
}

// ---------------------------------------------------------------------------
// K2: FUSED score+softmax+PV+FC.
// Block (jchunk jx, key-strip iy, batch b): computes S = K_strip . Q_tile^T
// and G = V_strip . Wfc_tile^T (two 128x128x1024 bf16 MFMA GEMMs, same C
// layout -> element-paired in registers), then p = exp(S*scale) (no max
// subtraction: |S*scale| <= ~2, fp32-safe; softmax is shift-invariant), and
// accumulates l_i += sum_q p, A_i += sum_q p*G via atomics (sums over q are
// block-partitionable).  out[b] = bfc + sum_i A_i/l_i  (finalize kernel).
// grid (8, 8, 16) block 256.
// ---------------------------------------------------------------------------
__global__ __launch_bounds__(256)
void fused_attn(const unsigned short* __restrict__ kbuf,
                const unsigned short* __restrict__ qbuf,
                const unsigned short* __restrict__ vbuf,
                const unsigned short* __restrict__ wfcb,
                float* __restrict__ lbuf, float* __restrict__ Abuf) {
    __shared__ __align__(16) unsigned short Ks[128 * 32];
    __shared__ __align__(16) unsigned short Vs[128 * 32];
    __shared__ __align__(16) unsigned short Qs[128 * 32];
    __shared__ __align__(16) unsigned short Ws[128 * 32];

    const int b  = blockIdx.z;
    const int j0 = blockIdx.x * 128;   // query chunk
    const int i0 = blockIdx.y * 128;   // key strip
    const unsigned short* K = kbuf + (size_t)b * T_ * D_;
    const unsigned short* Q = qbuf + (size_t)b * T_ * D_;
    const unsigned short* V = vbuf + (size_t)b * T_ * D_;

    const int tid = threadIdx.x, lane = tid & 63, wave = tid >> 6;
    const int wm = (wave >> 1) * 64, wn = (wave & 1) * 64;

    f32x4 accS[4][4], accG[4][4];
#pragma unroll
    for (int i = 0; i < 4; i++)
#pragma unroll
        for (int j = 0; j < 4; j++) {
            accS[i][j] = (f32x4){0.f, 0.f, 0.f, 0.f};
            accG[i][j] = (f32x4){0.f, 0.f, 0.f, 0.f};
        }

    const int srow = lane >> 2;          // row within 16-row group
    const int sk   = (lane & 3) * 8;     // k elem offset
    const int fr = lane & 15, fk = (lane >> 4) * 8;

    // wave roles for staging: wave0->Ks, wave1->Vs, wave2->Qs, wave3->Ws
    const unsigned short* gsrc;
    unsigned short* ldst;
    if (wave == 0)      { gsrc = K + (size_t)i0 * D_; ldst = Ks; }
    else if (wave == 1) { gsrc = V + (size_t)i0 * D_; ldst = Vs; }
    else if (wave == 2) { gsrc = Q + (size_t)j0 * D_; ldst = Qs; }
    else                { gsrc = wfcb + (size_t)j0 * D_; ldst = Ws; }

    for (int k0 = 0; k0 < D_; k0 += 32) {
#pragma unroll
        for (int g = 0; g < 8; ++g) {
            const int r = g * 16 + srow;
            __builtin_amdgcn_global_load_lds(
                (const __attribute__((address_space(1))) unsigned int*)
                    (gsrc + (size_t)r * D_ + k0 + sk),
                (__attribute__((address_space(3))) unsigned int*)(ldst + g * 512),
                16, 0, 0);
        }
        __syncthreads();

        frag8 bq_[4], bw_[4];
#pragma unroll
        for (int t = 0; t < 4; ++t) {
            bq_[t] = *(const frag8*)&Qs[(wn + t * 16 + fr) * 32 + fk];
            bw_[t] = *(const frag8*)&Ws[(wn + t * 16 + fr) * 32 + fk];
        }
#pragma unroll
        for (int i = 0; i < 4; i++) {
            frag8 ak_ = *(const frag8*)&Ks[(wm + i * 16 + fr) * 32 + fk];
            frag8 av_ = *(const frag8*)&Vs[(wm + i * 16 + fr) * 32 + fk];
#pragma unroll
            for (int j = 0; j < 4; j++) {
                accS[i][j] = __builtin_amdgcn_mfma_f32_16x16x32_bf16(
                    ak_, bq_[j], accS[i][j], 0, 0, 0);
                accG[i][j] = __builtin_amdgcn_mfma_f32_16x16x32_bf16(
                    av_, bw_[j], accG[i][j], 0, 0, 0);
            }
        }
        __syncthreads();
    }

    // epilogue: p = exp(S*scale); row partials over this block's q-range
    const float scale = 0.03125f;   // 1/sqrt(1024)
    float l_part[4][4], A_part[4][4];
#pragma unroll
    for (int i = 0; i < 4; i++)
#pragma unroll
        for (int r = 0; r < 4; r++) { l_part[i][r] = 0.f; A_part[i][r] = 0.f; }

#pragma unroll
    for (int i = 0; i < 4; i++)
#pragma unroll
        for (int j = 0; j < 4; j++)
#pragma unroll
            for (int r = 0; r < 4; r++) {
                float p = __expf(accS[i][j][r] * scale);
                l_part[i][r] += p;
                A_part[i][r] += p * accG[i][j][r];
            }

    // reduce across the 16 lanes sharing each C-row (lane&15 = col)
#pragma unroll
    for (int m = 1; m < 16; m <<= 1) {
#pragma unroll
        for (int i = 0; i < 4; i++)
#pragma unroll
            for (int r = 0; r < 4; r++) {
                l_part[i][r] += __shfl_xor(l_part[i][r], m);
                A_part[i][r] += __shfl_xor(A_part[i][r], m);
            }
    }

    if ((lane & 15) == 0) {
        const int rb = (lane >> 4) * 4;
        float* lrow = lbuf + (size_t)b * T_ + i0;
        float* Arow = Abuf + (size_t)b * T_ + i0;
#pragma unroll
        for (int i = 0; i < 4; i++)
#pragma unroll
            for (int r = 0; r < 4; r++) {
                int row = wm + i * 16 + rb + r;
                atomicAdd(&lrow[row], l_part[i][r]);
                atomicAdd(&Arow[row], A_part[i][r]);
            }
    }
}

// ---------------------------------------------------------------------------
// K3: finalize — out[b] = bfc + sum_i A_i / l_i.  grid (16) block 256.
// ---------------------------------------------------------------------------
__global__ __launch_bounds__(256)
void finalize(const float* __restrict__ lbuf, const float* __restrict__ Abuf,
              const float* __restrict__ bfc, float* __restrict__ out) {
    const int b = blockIdx.x;
    const int tid = threadIdx.x, lane = tid & 63, wave = tid >> 6;
    float s = 0.f;
#pragma unroll
    for (int p = 0; p < 4; ++p) {
        int i = tid + p * 256;
        s += Abuf[(size_t)b * T_ + i] / lbuf[(size_t)b * T_ + i];
    }
#pragma unroll
    for (int off = 32; off; off >>= 1) s += __shfl_down(s, off);
    __shared__ float ws_[4];
    if (lane == 0) ws_[wave] = s;
    __syncthreads();
    if (tid == 0) out[b] = ws_[0] + ws_[1] + ws_[2] + ws_[3] + bfc[0];
}

extern "C" void kernel_launch(void* const* d_in, const int* in_sizes, int n_in,
                              void* d_out, int out_size, void* d_ws, size_t ws_size,
                              hipStream_t stream) {
    const float* x   = (const float*)d_in[0];
    const float* Wq  = (const float*)d_in[1];
    const float* bq  = (const float*)d_in[2];
    const float* Wk  = (const float*)d_in[3];
    const float* bk  = (const float*)d_in[4];
    const float* Wv  = (const float*)d_in[5];
    const float* bv  = (const float*)d_in[6];
    const float* Wfc = (const float*)d_in[7];
    const float* bfc = (const float*)d_in[8];
    float* out = (float*)d_out;

    // workspace layout (~136 MB, no aliasing needed):
    char* ws = (char*)d_ws;
    unsigned short* xb   = (unsigned short*)ws;                         // 32 MB
    unsigned short* wt   = xb + (size_t)B_ * T_ * D_;                   // 6 MB
    unsigned short* wfcb = wt + (size_t)3 * D_ * D_;                    // 2 MB
    unsigned short* qb   = wfcb + (size_t)T_ * D_;                      // 32 MB
    unsigned short* kb   = qb + (size_t)B_ * T_ * D_;                   // 32 MB
    unsigned short* vb   = kb + (size_t)B_ * T_ * D_;                   // 32 MB
    float*          lbuf = (float*)(vb + (size_t)B_ * T_ * D_);         // 64 KB
    float*          Abuf = lbuf + (size_t)B_ * T_;                      // 64 KB

    cvt_x    <<<dim3(16384),     256, 0, stream>>>(x, xb);
    cvt_wt   <<<dim3(16, 16, 3), 256, 0, stream>>>(Wq, Wk, Wv, wt);
    cvt_wfc  <<<dim3(1024),      256, 0, stream>>>(Wfc, wfcb);
    hipMemsetAsync(lbuf, 0, (size_t)2 * B_ * T_ * sizeof(float), stream);
    qkv_gemm3<<<dim3(8, 128, 3), 256, 0, stream>>>(xb, wt, bq, bk, bv, qb, kb, vb);
    fused_attn<<<dim3(8, 8, 16), 256, 0, stream>>>(kb, qb, vb, wfcb, lbuf, Abuf);
    finalize <<<dim3(B_),        256, 0, stream>>>(lbuf, Abuf, bfc, out);
}

// Round 5
// 363.711 us; speedup vs baseline: 1.2126x; 1.2126x over previous
//
#include <hip/hip_runtime.h>
#include <hip/hip_bf16.h>

// Problem constants
#define B_ 16
#define T_ 1024
#define D_ 1024

using frag8 = __attribute__((ext_vector_type(8))) short;   // 8 bf16 (4 VGPRs)
using f32x4 = __attribute__((ext_vector_type(4))) float;   // 4 fp32 acc

__device__ inline unsigned short f2bf(float f) {
    union { float f; unsigned u; } v; v.f = f;
    unsigned r = v.u + 0x7FFF + ((v.u >> 16) & 1);   // round-nearest-even
    return (unsigned short)(r >> 16);
}
__device__ inline float bf2f(unsigned short u) {
    union { unsigned u; float f; } v; v.u = ((unsigned)u) << 16;
    return v.f;
}

// ---------------------------------------------------------------------------
// K0a: x fp32 -> bf16  (16M elems, float4 in / ushort4 out, pure BW)
// ---------------------------------------------------------------------------
__global__ __launch_bounds__(256)
void cvt_x(const float* __restrict__ x, unsigned short* __restrict__ xb) {
    int i = blockIdx.x * 256 + threadIdx.x;          // group of 4 elems
    float4 v = ((const float4*)x)[i];
    ushort4 o;
    o.x = f2bf(v.x); o.y = f2bf(v.y); o.z = f2bf(v.z); o.w = f2bf(v.w);
    ((ushort4*)xb)[i] = o;
}

// ---------------------------------------------------------------------------
// K0b: W fp32 [k][n] -> bf16 TRANSPOSED wt[z][n][k]  (64x64 LDS tile transpose)
// grid (16,16,3) block 256
// ---------------------------------------------------------------------------
__global__ __launch_bounds__(256)
void cvt_wt(const float* __restrict__ Wq, const float* __restrict__ Wk,
            const float* __restrict__ Wv, unsigned short* __restrict__ wt) {
    __shared__ unsigned short t[64][65];
    const float* W = (blockIdx.z == 0) ? Wq : (blockIdx.z == 1 ? Wk : Wv);
    const int n0 = blockIdx.x * 64, k0 = blockIdx.y * 64;
    const int tn = threadIdx.x & 63;   // coalesced over n
    const int tk = threadIdx.x >> 6;   // 0..3
#pragma unroll
    for (int it = 0; it < 16; ++it) {
        int k = tk + it * 4;
        t[tn][k] = f2bf(W[(size_t)(k0 + k) * D_ + n0 + tn]);
    }
    __syncthreads();
    const int wk = threadIdx.x & 63;   // coalesced over k
    const int wn = threadIdx.x >> 6;
#pragma unroll
    for (int it = 0; it < 16; ++it) {
        int n = wn + it * 4;
        wt[((size_t)blockIdx.z << 20) + (size_t)(n0 + n) * D_ + k0 + wk] = t[n][wk];
    }
}

// ---------------------------------------------------------------------------
// K0c: Wfc fp32 (1M flat, = [q][d] row-major) -> bf16 (2 MB, L2-resident)
// grid 1024 x 256
// ---------------------------------------------------------------------------
__global__ __launch_bounds__(256)
void cvt_wfc(const float* __restrict__ wfc, unsigned short* __restrict__ wb) {
    int i = blockIdx.x * 256 + threadIdx.x;
    float4 v = ((const float4*)wfc)[i];
    ushort4 o;
    o.x = f2bf(v.x); o.y = f2bf(v.y); o.z = f2bf(v.z); o.w = f2bf(v.w);
    ((ushort4*)wb)[i] = o;
}

// ---------------------------------------------------------------------------
// K1: fused Q/K/V projection, m97-style staging (unchanged from R4).
// grid: (8, 128, 3) linear = x + 8*y + 1024*z.   block: 256
// ---------------------------------------------------------------------------
__global__ __launch_bounds__(256)
void qkv_gemm3(const unsigned short* __restrict__ xb,
               const unsigned short* __restrict__ wt,
               const float* __restrict__ bq, const float* __restrict__ bk,
               const float* __restrict__ bv,
               unsigned short* __restrict__ qb,
               unsigned short* __restrict__ kb,
               unsigned short* __restrict__ vb) {
    __shared__ __align__(16) unsigned short As[128 * 32];
    __shared__ __align__(16) unsigned short Bs[128 * 32];

    const int l    = blockIdx.x + 8 * blockIdx.y + 1024 * blockIdx.z;
    const int xcd  = l & 7;
    const int idx  = l >> 3;            // 0..383
    const int sgrp = idx / 48;          // slab group 0..7
    const int rem  = idx - sgrp * 48;
    const int mgrp = rem / 3;           // 0..15
    const int s_in = rem - mgrp * 3;    // 0..2
    const int slab = sgrp * 3 + s_in;   // 0..23
    const int mblk = xcd * 16 + mgrp;   // 0..127
    const int z    = slab >> 3;
    const int nblk = slab & 7;

    const int m0 = mblk * 128, n0 = nblk * 128;
    const unsigned short* Wz = wt + ((size_t)z << 20);
    const float* bias  = (z == 0) ? bq : (z == 1 ? bk : bv);
    unsigned short* out = (z == 0) ? qb : (z == 1 ? kb : vb);

    const int tid = threadIdx.x, lane = tid & 63, wave = tid >> 6;
    const int wm = (wave >> 1) * 64, wn = (wave & 1) * 64;

    f32x4 acc[4][4];
#pragma unroll
    for (int i = 0; i < 4; i++)
#pragma unroll
        for (int j = 0; j < 4; j++) acc[i][j] = (f32x4){0.f, 0.f, 0.f, 0.f};

    const int srow = lane >> 2;          // row within 16-row group
    const int sk   = (lane & 3) * 8;     // k elem offset
    const int fr = lane & 15, fk = (lane >> 4) * 8;

    for (int k0 = 0; k0 < D_; k0 += 32) {
#pragma unroll
        for (int it = 0; it < 2; ++it) {
            const int rb = wave * 2 + it;           // 16-row group 0..7
            const int r  = rb * 16 + srow;
            __builtin_amdgcn_global_load_lds(
                (const __attribute__((address_space(1))) unsigned int*)
                    (xb + (size_t)(m0 + r) * D_ + k0 + sk),
                (__attribute__((address_space(3))) unsigned int*)(As + rb * 512),
                16, 0, 0);
            __builtin_amdgcn_global_load_lds(
                (const __attribute__((address_space(1))) unsigned int*)
                    (Wz + (size_t)(n0 + r) * D_ + k0 + sk),
                (__attribute__((address_space(3))) unsigned int*)(Bs + rb * 512),
                16, 0, 0);
        }
        __syncthreads();

        frag8 af[4], bff[4];
#pragma unroll
        for (int t = 0; t < 4; ++t)
            af[t] = *(const frag8*)&As[(wm + t * 16 + fr) * 32 + fk];
#pragma unroll
        for (int t = 0; t < 4; ++t)
            bff[t] = *(const frag8*)&Bs[(wn + t * 16 + fr) * 32 + fk];
#pragma unroll
        for (int i = 0; i < 4; i++)
#pragma unroll
            for (int j = 0; j < 4; j++)
                acc[i][j] = __builtin_amdgcn_mfma_f32_16x16x32_bf16(
                    af[i], bff[j], acc[i][j], 0, 0, 0);
        __syncthreads();
    }

    const int col   = lane & 15;
    const int rbase = (lane >> 4) * 4;
#pragma unroll
    for (int i = 0; i < 4; i++) {
#pragma unroll
        for (int j = 0; j < 4; j++) {
            int gn = n0 + wn + j * 16 + col;
            float bb = bias[gn];
#pragma unroll
            for (int r = 0; r < 4; r++) {
                int gm = m0 + wm + i * 16 + rbase + r;
                out[(size_t)gm * D_ + gn] = f2bf(acc[i][j][r] + bb);
            }
        }
    }
}

// ---------------------------------------------------------------------------
// K2: G = V . Wfc^T  (m97-style).  G[b*T + i][q] = sum_d V[b][i][d]*Wfc[q][d]
// M = B*T = 16384 rows, N = 1024 (q), K = 1024 (d).  Output bf16 (32 MB).
// XCD swizzle: each XCD owns 16 m-blocks (4 MB of V, L2-resident); Wfc (2 MB)
// streams to every XCD. grid (8, 128) block 256, linear = x + 8*y.
// ---------------------------------------------------------------------------
__global__ __launch_bounds__(256)
void g_gemm(const unsigned short* __restrict__ vbuf,
            const unsigned short* __restrict__ wfcb,
            unsigned short* __restrict__ gb) {
    __shared__ __align__(16) unsigned short As[128 * 32];
    __shared__ __align__(16) unsigned short Bs[128 * 32];

    const int l   = blockIdx.x + 8 * blockIdx.y;
    const int xcd = l & 7;
    const int u   = l >> 3;             // 0..127
    const int m0  = (xcd * 16 + (u >> 3)) * 128;
    const int n0  = (u & 7) * 128;

    const int tid = threadIdx.x, lane = tid & 63, wave = tid >> 6;
    const int wm = (wave >> 1) * 64, wn = (wave & 1) * 64;

    f32x4 acc[4][4];
#pragma unroll
    for (int i = 0; i < 4; i++)
#pragma unroll
        for (int j = 0; j < 4; j++) acc[i][j] = (f32x4){0.f, 0.f, 0.f, 0.f};

    const int srow = lane >> 2;
    const int sk   = (lane & 3) * 8;
    const int fr = lane & 15, fk = (lane >> 4) * 8;

    for (int k0 = 0; k0 < D_; k0 += 32) {
#pragma unroll
        for (int it = 0; it < 2; ++it) {
            const int rb = wave * 2 + it;
            const int r  = rb * 16 + srow;
            __builtin_amdgcn_global_load_lds(
                (const __attribute__((address_space(1))) unsigned int*)
                    (vbuf + (size_t)(m0 + r) * D_ + k0 + sk),
                (__attribute__((address_space(3))) unsigned int*)(As + rb * 512),
                16, 0, 0);
            __builtin_amdgcn_global_load_lds(
                (const __attribute__((address_space(1))) unsigned int*)
                    (wfcb + (size_t)(n0 + r) * D_ + k0 + sk),
                (__attribute__((address_space(3))) unsigned int*)(Bs + rb * 512),
                16, 0, 0);
        }
        __syncthreads();

        frag8 af[4], bff[4];
#pragma unroll
        for (int t = 0; t < 4; ++t)
            af[t] = *(const frag8*)&As[(wm + t * 16 + fr) * 32 + fk];
#pragma unroll
        for (int t = 0; t < 4; ++t)
            bff[t] = *(const frag8*)&Bs[(wn + t * 16 + fr) * 32 + fk];
#pragma unroll
        for (int i = 0; i < 4; i++)
#pragma unroll
            for (int j = 0; j < 4; j++)
                acc[i][j] = __builtin_amdgcn_mfma_f32_16x16x32_bf16(
                    af[i], bff[j], acc[i][j], 0, 0, 0);
        __syncthreads();
    }

    const int col   = lane & 15;
    const int rbase = (lane >> 4) * 4;
#pragma unroll
    for (int i = 0; i < 4; i++) {
#pragma unroll
        for (int j = 0; j < 4; j++) {
            int gn = n0 + wn + j * 16 + col;
#pragma unroll
            for (int r = 0; r < 4; r++) {
                int gm = m0 + wm + i * 16 + rbase + r;
                gb[(size_t)gm * T_ + gn] = f2bf(acc[i][j][r]);
            }
        }
    }
}

// ---------------------------------------------------------------------------
// K3: score + exp + G-weighted row reduction (single C-tile version).
// Block (j0 chunk, i0 strip, b): S = K_strip . Q_chunk^T (128x128x1024 MFMA),
// p = exp(S*scale) (no max needed: |S*scale| <= ~2), then
//   l_i += sum_q p,  A_i += sum_q p * G[b*T+i][q]   (atomics over j0 blocks).
// XCD swizzle: XCD owns 2 batches; i0 outer, j0 inner -> K strip reused 8x
// from L2, Q[b] (2 MB) L2-resident. grid (8, 8, 16) -> linear decode.
// ---------------------------------------------------------------------------
__global__ __launch_bounds__(256)
void score_attn(const unsigned short* __restrict__ kbuf,
                const unsigned short* __restrict__ qbuf,
                const unsigned short* __restrict__ gb,
                float* __restrict__ lbuf, float* __restrict__ Abuf) {
    __shared__ __align__(16) unsigned short Ks[128 * 32];
    __shared__ __align__(16) unsigned short Qs[128 * 32];

    const int l   = blockIdx.x + 8 * blockIdx.y + 64 * blockIdx.z;
    const int xcd = l & 7;
    const int u   = l >> 3;            // 0..127
    const int i0b = u >> 4;            // 0..7  (i0 outer)
    const int mid = u & 15;
    const int b   = xcd * 2 + (mid >> 3);
    const int j0b = mid & 7;           // j0 inner
    const int i0 = i0b * 128, j0 = j0b * 128;

    const unsigned short* K = kbuf + (size_t)b * T_ * D_;
    const unsigned short* Q = qbuf + (size_t)b * T_ * D_;

    const int tid = threadIdx.x, lane = tid & 63, wave = tid >> 6;
    const int wm = (wave >> 1) * 64, wn = (wave & 1) * 64;

    f32x4 accS[4][4];
#pragma unroll
    for (int i = 0; i < 4; i++)
#pragma unroll
        for (int j = 0; j < 4; j++) accS[i][j] = (f32x4){0.f, 0.f, 0.f, 0.f};

    const int srow = lane >> 2;
    const int sk   = (lane & 3) * 8;
    const int fr = lane & 15, fk = (lane >> 4) * 8;

    for (int k0 = 0; k0 < D_; k0 += 32) {
#pragma unroll
        for (int it = 0; it < 2; ++it) {
            const int rb = wave * 2 + it;
            const int r  = rb * 16 + srow;
            __builtin_amdgcn_global_load_lds(
                (const __attribute__((address_space(1))) unsigned int*)
                    (K + (size_t)(i0 + r) * D_ + k0 + sk),
                (__attribute__((address_space(3))) unsigned int*)(Ks + rb * 512),
                16, 0, 0);
            __builtin_amdgcn_global_load_lds(
                (const __attribute__((address_space(1))) unsigned int*)
                    (Q + (size_t)(j0 + r) * D_ + k0 + sk),
                (__attribute__((address_space(3))) unsigned int*)(Qs + rb * 512),
                16, 0, 0);
        }
        __syncthreads();

        frag8 af[4], bff[4];
#pragma unroll
        for (int t = 0; t < 4; ++t)
            af[t] = *(const frag8*)&Ks[(wm + t * 16 + fr) * 32 + fk];
#pragma unroll
        for (int t = 0; t < 4; ++t)
            bff[t] = *(const frag8*)&Qs[(wn + t * 16 + fr) * 32 + fk];
#pragma unroll
        for (int i = 0; i < 4; i++)
#pragma unroll
            for (int j = 0; j < 4; j++)
                accS[i][j] = __builtin_amdgcn_mfma_f32_16x16x32_bf16(
                    af[i], bff[j], accS[i][j], 0, 0, 0);
        __syncthreads();
    }

    // epilogue: p = exp(S*scale), pair with G tile, row partials over q
    const float scale = 0.03125f;   // 1/sqrt(1024)
    const int col   = lane & 15;
    const int rbase = (lane >> 4) * 4;
    const unsigned short* Gt = gb + ((size_t)b * T_ + i0) * T_ + j0;

    float l_part[4][4], A_part[4][4];
#pragma unroll
    for (int i = 0; i < 4; i++)
#pragma unroll
        for (int r = 0; r < 4; r++) { l_part[i][r] = 0.f; A_part[i][r] = 0.f; }

#pragma unroll
    for (int i = 0; i < 4; i++)
#pragma unroll
        for (int j = 0; j < 4; j++) {
            const int gq = wn + j * 16 + col;
#pragma unroll
            for (int r = 0; r < 4; r++) {
                const int gi = wm + i * 16 + rbase + r;
                float p = __expf(accS[i][j][r] * scale);
                float g = bf2f(Gt[(size_t)gi * T_ + gq]);
                l_part[i][r] += p;
                A_part[i][r] += p * g;
            }
        }

    // reduce across the 16 lanes sharing each C-row (lane&15 = col)
#pragma unroll
    for (int m = 1; m < 16; m <<= 1) {
#pragma unroll
        for (int i = 0; i < 4; i++)
#pragma unroll
            for (int r = 0; r < 4; r++) {
                l_part[i][r] += __shfl_xor(l_part[i][r], m);
                A_part[i][r] += __shfl_xor(A_part[i][r], m);
            }
    }

    if ((lane & 15) == 0) {
        float* lrow = lbuf + (size_t)b * T_ + i0;
        float* Arow = Abuf + (size_t)b * T_ + i0;
#pragma unroll
        for (int i = 0; i < 4; i++)
#pragma unroll
            for (int r = 0; r < 4; r++) {
                int row = wm + i * 16 + rbase + r;
                atomicAdd(&lrow[row], l_part[i][r]);
                atomicAdd(&Arow[row], A_part[i][r]);
            }
    }
}

// ---------------------------------------------------------------------------
// K4: finalize — out[b] = bfc + sum_i A_i / l_i.  grid (16) block 256.
// ---------------------------------------------------------------------------
__global__ __launch_bounds__(256)
void finalize(const float* __restrict__ lbuf, const float* __restrict__ Abuf,
              const float* __restrict__ bfc, float* __restrict__ out) {
    const int b = blockIdx.x;
    const int tid = threadIdx.x, lane = tid & 63, wave = tid >> 6;
    float s = 0.f;
#pragma unroll
    for (int p = 0; p < 4; ++p) {
        int i = tid + p * 256;
        s += Abuf[(size_t)b * T_ + i] / lbuf[(size_t)b * T_ + i];
    }
#pragma unroll
    for (int off = 32; off; off >>= 1) s += __shfl_down(s, off);
    __shared__ float ws_[4];
    if (lane == 0) ws_[wave] = s;
    __syncthreads();
    if (tid == 0) out[b] = ws_[0] + ws_[1] + ws_[2] + ws_[3] + bfc[0];
}

extern "C" void kernel_launch(void* const* d_in, const int* in_sizes, int n_in,
                              void* d_out, int out_size, void* d_ws, size_t ws_size,
                              hipStream_t stream) {
    const float* x   = (const float*)d_in[0];
    const float* Wq  = (const float*)d_in[1];
    const float* bq  = (const float*)d_in[2];
    const float* Wk  = (const float*)d_in[3];
    const float* bk  = (const float*)d_in[4];
    const float* Wv  = (const float*)d_in[5];
    const float* bv  = (const float*)d_in[6];
    const float* Wfc = (const float*)d_in[7];
    const float* bfc = (const float*)d_in[8];
    float* out = (float*)d_out;

    // workspace layout (~168 MB):
    char* ws = (char*)d_ws;
    unsigned short* xb   = (unsigned short*)ws;                         // 32 MB
    unsigned short* wt   = xb + (size_t)B_ * T_ * D_;                   // 6 MB
    unsigned short* wfcb = wt + (size_t)3 * D_ * D_;                    // 2 MB
    unsigned short* qb   = wfcb + (size_t)T_ * D_;                      // 32 MB
    unsigned short* kb   = qb + (size_t)B_ * T_ * D_;                   // 32 MB
    unsigned short* vb   = kb + (size_t)B_ * T_ * D_;                   // 32 MB
    unsigned short* gb   = vb + (size_t)B_ * T_ * D_;                   // 32 MB
    float*          lbuf = (float*)(gb + (size_t)B_ * T_ * T_);         // 64 KB
    float*          Abuf = lbuf + (size_t)B_ * T_;                      // 64 KB

    cvt_x     <<<dim3(16384),     256, 0, stream>>>(x, xb);
    cvt_wt    <<<dim3(16, 16, 3), 256, 0, stream>>>(Wq, Wk, Wv, wt);
    cvt_wfc   <<<dim3(1024),      256, 0, stream>>>(Wfc, wfcb);
    hipMemsetAsync(lbuf, 0, (size_t)2 * B_ * T_ * sizeof(float), stream);
    qkv_gemm3 <<<dim3(8, 128, 3), 256, 0, stream>>>(xb, wt, bq, bk, bv, qb, kb, vb);
    g_gemm    <<<dim3(8, 128),    256, 0, stream>>>(vb, wfcb, gb);
    score_attn<<<dim3(8, 8, 16),  256, 0, stream>>>(kb, qb, gb, lbuf, Abuf);
    finalize  <<<dim3(B_),        256, 0, stream>>>(lbuf, Abuf, bfc, out);
}

// Round 7
// 318.518 us; speedup vs baseline: 1.3846x; 1.1419x over previous
//
#include <hip/hip_runtime.h>
#include <hip/hip_bf16.h>

// Problem constants
#define B_ 16
#define T_ 1024
#define D_ 1024

using frag8 = __attribute__((ext_vector_type(8))) short;   // 8 bf16 (4 VGPRs)
using f32x4 = __attribute__((ext_vector_type(4))) float;   // 4 fp32 acc

__device__ inline unsigned short f2bf(float f) {
    union { float f; unsigned u; } v; v.f = f;
    unsigned r = v.u + 0x7FFF + ((v.u >> 16) & 1);   // round-nearest-even
    return (unsigned short)(r >> 16);
}
__device__ inline float bf2f(unsigned short u) {
    union { unsigned u; float f; } v; v.u = ((unsigned)u) << 16;
    return v.f;
}

// ---------------------------------------------------------------------------
// K0a: x fp32 -> bf16  (16M elems)
// ---------------------------------------------------------------------------
__global__ __launch_bounds__(256)
void cvt_x(const float* __restrict__ x, unsigned short* __restrict__ xb) {
    int i = blockIdx.x * 256 + threadIdx.x;
    float4 v = ((const float4*)x)[i];
    ushort4 o;
    o.x = f2bf(v.x); o.y = f2bf(v.y); o.z = f2bf(v.z); o.w = f2bf(v.w);
    ((ushort4*)xb)[i] = o;
}

// ---------------------------------------------------------------------------
// K0b: plain-cast Wq/Wk/Wv/Wfc fp32 -> bf16 (no transpose; all used k-major).
// grid 4096: w = bx>>10 selects the weight.
// ---------------------------------------------------------------------------
__global__ __launch_bounds__(256)
void cvt_w4(const float* __restrict__ Wq, const float* __restrict__ Wk,
            const float* __restrict__ Wv, const float* __restrict__ Wfc,
            unsigned short* __restrict__ wqb, unsigned short* __restrict__ wkb,
            unsigned short* __restrict__ wvb, unsigned short* __restrict__ wfcb) {
    const int w = blockIdx.x >> 10;
    const float* src = (w == 0) ? Wq : (w == 1) ? Wk : (w == 2) ? Wv : Wfc;
    unsigned short* dst = (w == 0) ? wqb : (w == 1) ? wkb : (w == 2) ? wvb : wfcb;
    int i = (blockIdx.x & 1023) * 256 + threadIdx.x;
    float4 v = ((const float4*)src)[i];
    ushort4 o;
    o.x = f2bf(v.x); o.y = f2bf(v.y); o.z = f2bf(v.z); o.w = f2bf(v.w);
    ((ushort4*)dst)[i] = o;
}

// ---------------------------------------------------------------------------
// K0c: weight-bias vectors (fp32, exact):
//  y=0: w1[e] = Wk[e]·bq     y=1: w2[e] = Wq[e]·bk
//  y=2: c[q]  = Wfc_row(q)·bv   y=3 (block 0 only): bkbq = bk·bq
// grid (256, 4), block 256 (4 waves, 1 row/wave).
// ---------------------------------------------------------------------------
__global__ __launch_bounds__(256)
void wvec(const float* __restrict__ Wq, const float* __restrict__ Wk,
          const float* __restrict__ Wfc,
          const float* __restrict__ bq, const float* __restrict__ bk,
          const float* __restrict__ bv,
          float* __restrict__ w1, float* __restrict__ w2,
          float* __restrict__ cvec, float* __restrict__ bkbq) {
    const int y = blockIdx.y;
    const int tid = threadIdx.x, lane = tid & 63, wave = tid >> 6;
    if (y == 3) {
        if (blockIdx.x != 0) return;
        float s = 0.f;
#pragma unroll
        for (int p = 0; p < 4; ++p) { int i = tid + p * 256; s += bk[i] * bq[i]; }
#pragma unroll
        for (int off = 32; off; off >>= 1) s += __shfl_down(s, off);
        __shared__ float sm[4];
        if (lane == 0) sm[wave] = s;
        __syncthreads();
        if (tid == 0) bkbq[0] = sm[0] + sm[1] + sm[2] + sm[3];
        return;
    }
    const float* Wsrc; const float* bvv; float* outp;
    if (y == 0)      { Wsrc = Wk;  bvv = bq; outp = w1; }
    else if (y == 1) { Wsrc = Wq;  bvv = bk; outp = w2; }
    else             { Wsrc = Wfc; bvv = bv; outp = cvec; }
    const int row = blockIdx.x * 4 + wave;
    const float* r = Wsrc + (size_t)row * D_;
    float s = 0.f;
#pragma unroll
    for (int it = 0; it < 4; ++it) {
        float4 a = *(const float4*)&r[it * 256 + lane * 4];
        float4 b = *(const float4*)&bvv[it * 256 + lane * 4];
        s += a.x * b.x + a.y * b.y + a.z * b.z + a.w * b.w;
    }
#pragma unroll
    for (int off = 32; off; off >>= 1) s += __shfl_down(s, off);
    if (lane == 0) outp[row] = s;
}

// ---------------------------------------------------------------------------
// K1: small weight-product GEMMs (m97-style), 1024x1024x1024 each:
//  z=0: NT[f][e] = sum_d Wq[f][d]·Wk[e][d]   -> ntb
//  z=1: M [q][e] = sum_d Wfc[q][d]·Wv[e][d]  -> mb
// grid (8, 8, 2) block 256.
// ---------------------------------------------------------------------------
__global__ __launch_bounds__(256)
void small_gemm(const unsigned short* __restrict__ wqb,
                const unsigned short* __restrict__ wkb,
                const unsigned short* __restrict__ wfcb,
                const unsigned short* __restrict__ wvb,
                unsigned short* __restrict__ ntb,
                unsigned short* __restrict__ mb) {
    __shared__ __align__(16) unsigned short As[128 * 32];
    __shared__ __align__(16) unsigned short Bs[128 * 32];

    const int z  = blockIdx.z;
    const int n0 = blockIdx.x * 128;
    const int m0 = blockIdx.y * 128;
    const unsigned short* A  = z ? wfcb : wqb;
    const unsigned short* Bm = z ? wvb  : wkb;
    unsigned short* out = z ? mb : ntb;

    const int tid = threadIdx.x, lane = tid & 63, wave = tid >> 6;
    const int wm = (wave >> 1) * 64, wn = (wave & 1) * 64;

    f32x4 acc[4][4];
#pragma unroll
    for (int i = 0; i < 4; i++)
#pragma unroll
        for (int j = 0; j < 4; j++) acc[i][j] = (f32x4){0.f, 0.f, 0.f, 0.f};

    const int srow = lane >> 2;
    const int sk   = (lane & 3) * 8;
    const int fr = lane & 15, fk = (lane >> 4) * 8;

    for (int k0 = 0; k0 < D_; k0 += 32) {
#pragma unroll
        for (int it = 0; it < 2; ++it) {
            const int rb = wave * 2 + it;
            const int r  = rb * 16 + srow;
            __builtin_amdgcn_global_load_lds(
                (const __attribute__((address_space(1))) unsigned int*)
                    (A + (size_t)(m0 + r) * D_ + k0 + sk),
                (__attribute__((address_space(3))) unsigned int*)(As + rb * 512),
                16, 0, 0);
            __builtin_amdgcn_global_load_lds(
                (const __attribute__((address_space(1))) unsigned int*)
                    (Bm + (size_t)(n0 + r) * D_ + k0 + sk),
                (__attribute__((address_space(3))) unsigned int*)(Bs + rb * 512),
                16, 0, 0);
        }
        __syncthreads();

        frag8 af[4], bff[4];
#pragma unroll
        for (int t = 0; t < 4; ++t)
            af[t] = *(const frag8*)&As[(wm + t * 16 + fr) * 32 + fk];
#pragma unroll
        for (int t = 0; t < 4; ++t)
            bff[t] = *(const frag8*)&Bs[(wn + t * 16 + fr) * 32 + fk];
#pragma unroll
        for (int i = 0; i < 4; i++)
#pragma unroll
            for (int j = 0; j < 4; j++)
                acc[i][j] = __builtin_amdgcn_mfma_f32_16x16x32_bf16(
                    af[i], bff[j], acc[i][j], 0, 0, 0);
        __syncthreads();
    }

    const int col   = lane & 15;
    const int rbase = (lane >> 4) * 4;
#pragma unroll
    for (int i = 0; i < 4; i++) {
#pragma unroll
        for (int j = 0; j < 4; j++) {
            int gn = n0 + wn + j * 16 + col;
#pragma unroll
            for (int r = 0; r < 4; r++) {
                int gm = m0 + wm + i * 16 + rbase + r;
                out[(size_t)gm * D_ + gn] = f2bf(acc[i][j][r]);
            }
        }
    }
}

// ---------------------------------------------------------------------------
// K2: u[i] = x[i]·w1,  v[i] = x[i]·w2 + bkbq.  1 row/wave, grid 4096.
// ---------------------------------------------------------------------------
__global__ __launch_bounds__(256)
void uv_kernel(const unsigned short* __restrict__ xb,
               const float* __restrict__ w1, const float* __restrict__ w2,
               const float* __restrict__ bkbq,
               float* __restrict__ u, float* __restrict__ v) {
    __shared__ float s1[1024], s2[1024];
    const int tid = threadIdx.x, lane = tid & 63, wave = tid >> 6;
#pragma unroll
    for (int p = 0; p < 4; ++p) {
        int i = tid + p * 256;
        s1[i] = w1[i]; s2[i] = w2[i];
    }
    __syncthreads();
    const int row = blockIdx.x * 4 + wave;
    const unsigned short* xr = xb + (size_t)row * D_;
    float du = 0.f, dv = 0.f;
#pragma unroll
    for (int it = 0; it < 2; ++it) {
        const int base = it * 512 + lane * 8;
        ushort4 a0 = *(const ushort4*)&xr[base];
        ushort4 a1 = *(const ushort4*)&xr[base + 4];
        float xv[8] = {bf2f(a0.x), bf2f(a0.y), bf2f(a0.z), bf2f(a0.w),
                       bf2f(a1.x), bf2f(a1.y), bf2f(a1.z), bf2f(a1.w)};
        float4 b0 = *(const float4*)&s1[base];
        float4 b1 = *(const float4*)&s1[base + 4];
        float4 c0 = *(const float4*)&s2[base];
        float4 c1 = *(const float4*)&s2[base + 4];
        du += xv[0]*b0.x + xv[1]*b0.y + xv[2]*b0.z + xv[3]*b0.w
            + xv[4]*b1.x + xv[5]*b1.y + xv[6]*b1.z + xv[7]*b1.w;
        dv += xv[0]*c0.x + xv[1]*c0.y + xv[2]*c0.z + xv[3]*c0.w
            + xv[4]*c1.x + xv[5]*c1.y + xv[6]*c1.z + xv[7]*c1.w;
    }
#pragma unroll
    for (int off = 32; off; off >>= 1) {
        du += __shfl_down(du, off);
        dv += __shfl_down(dv, off);
    }
    if (lane == 0) { u[row] = du; v[row] = dv + bkbq[0]; }
}

// ---------------------------------------------------------------------------
// K3: fused P/G GEMM.  Both share A = xb (M=16384, K=1024, N=1024):
//  z=0: P[i][f] = sum_e x[i][e]·NT[f][e]           -> pb  (bf16)
//  z=1: G[i][q] = sum_e x[i][e]·M[q][e] + c[q]     -> gbuf (bf16)
// XCD swizzle: each XCD owns 16 m-blocks (4 MB of x, L2-resident) across
// both z and all 8 n-blocks.  grid (8, 128, 2), linear = x + 8y + 1024z.
// ---------------------------------------------------------------------------
__global__ __launch_bounds__(256)
void pg_gemm(const unsigned short* __restrict__ xb,
             const unsigned short* __restrict__ ntb,
             const unsigned short* __restrict__ mb,
             const float* __restrict__ cvec,
             unsigned short* __restrict__ pb,
             unsigned short* __restrict__ gbuf) {
    __shared__ __align__(16) unsigned short As[128 * 32];
    __shared__ __align__(16) unsigned short Bs[128 * 32];

    const int l    = blockIdx.x + 8 * blockIdx.y + 1024 * blockIdx.z;
    const int xcd  = l & 7;
    const int idx  = l >> 3;            // 0..255
    const int mblk = xcd * 16 + (idx & 15);
    const int rest = idx >> 4;          // 0..15
    const int z    = rest >> 3;
    const int n0   = (rest & 7) * 128;
    const int m0   = mblk * 128;

    const unsigned short* Bm = z ? mb : ntb;
    unsigned short* out = z ? gbuf : pb;

    const int tid = threadIdx.x, lane = tid & 63, wave = tid >> 6;
    const int wm = (wave >> 1) * 64, wn = (wave & 1) * 64;

    f32x4 acc[4][4];
#pragma unroll
    for (int i = 0; i < 4; i++)
#pragma unroll
        for (int j = 0; j < 4; j++) acc[i][j] = (f32x4){0.f, 0.f, 0.f, 0.f};

    const int srow = lane >> 2;
    const int sk   = (lane & 3) * 8;
    const int fr = lane & 15, fk = (lane >> 4) * 8;

    for (int k0 = 0; k0 < D_; k0 += 32) {
#pragma unroll
        for (int it = 0; it < 2; ++it) {
            const int rb = wave * 2 + it;
            const int r  = rb * 16 + srow;
            __builtin_amdgcn_global_load_lds(
                (const __attribute__((address_space(1))) unsigned int*)
                    (xb + (size_t)(m0 + r) * D_ + k0 + sk),
                (__attribute__((address_space(3))) unsigned int*)(As + rb * 512),
                16, 0, 0);
            __builtin_amdgcn_global_load_lds(
                (const __attribute__((address_space(1))) unsigned int*)
                    (Bm + (size_t)(n0 + r) * D_ + k0 + sk),
                (__attribute__((address_space(3))) unsigned int*)(Bs + rb * 512),
                16, 0, 0);
        }
        __syncthreads();

        frag8 af[4], bff[4];
#pragma unroll
        for (int t = 0; t < 4; ++t)
            af[t] = *(const frag8*)&As[(wm + t * 16 + fr) * 32 + fk];
#pragma unroll
        for (int t = 0; t < 4; ++t)
            bff[t] = *(const frag8*)&Bs[(wn + t * 16 + fr) * 32 + fk];
#pragma unroll
        for (int i = 0; i < 4; i++)
#pragma unroll
            for (int j = 0; j < 4; j++)
                acc[i][j] = __builtin_amdgcn_mfma_f32_16x16x32_bf16(
                    af[i], bff[j], acc[i][j], 0, 0, 0);
        __syncthreads();
    }

    const int col   = lane & 15;
    const int rbase = (lane >> 4) * 4;
#pragma unroll
    for (int i = 0; i < 4; i++) {
#pragma unroll
        for (int j = 0; j < 4; j++) {
            int gn = n0 + wn + j * 16 + col;
            float bb = z ? cvec[gn] : 0.f;
#pragma unroll
            for (int r = 0; r < 4; r++) {
                int gm = m0 + wm + i * 16 + rbase + r;
                out[(size_t)gm * D_ + gn] = f2bf(acc[i][j][r] + bb);
            }
        }
    }
}

// ---------------------------------------------------------------------------
// K4: score + exp + G-weighted row reduction — DETERMINISTIC (no atomics).
// S[i][j] = sum_f P[b·T+i][f]·x[b·T+j][f] + u[b·T+i] + v[b·T+j]
// p = exp(S*scale).  Each block (b,i0b,j0b) writes per-column-half row
// partials:  lpart/Apart[(((b*8+i0b)*8+j0b)*2+half)*128 + row].
// Waves 0/2 produce half 0 (cols 0..63), waves 1/3 half 1 — every slot
// written exactly once per launch; finalize sums in fixed order.
// grid (8,8,16) block 256, XCD swizzle as before.
// ---------------------------------------------------------------------------
__global__ __launch_bounds__(256)
void score_attn(const unsigned short* __restrict__ pbuf,
                const unsigned short* __restrict__ xb,
                const unsigned short* __restrict__ gb,
                const float* __restrict__ u, const float* __restrict__ v,
                float* __restrict__ lpart, float* __restrict__ Apart) {
    __shared__ __align__(16) unsigned short Ks[128 * 32];
    __shared__ __align__(16) unsigned short Qs[128 * 32];

    const int l   = blockIdx.x + 8 * blockIdx.y + 64 * blockIdx.z;
    const int xcd = l & 7;
    const int uix = l >> 3;            // 0..127
    const int i0b = uix >> 4;          // 0..7  (i0 outer)
    const int mid = uix & 15;
    const int b   = xcd * 2 + (mid >> 3);
    const int j0b = mid & 7;           // j0 inner
    const int i0 = i0b * 128, j0 = j0b * 128;

    const unsigned short* P = pbuf + ((size_t)b * T_ + i0) * D_;
    const unsigned short* X = xb   + ((size_t)b * T_ + j0) * D_;

    const int tid = threadIdx.x, lane = tid & 63, wave = tid >> 6;
    const int wm = (wave >> 1) * 64, wn = (wave & 1) * 64;

    f32x4 accS[4][4];
#pragma unroll
    for (int i = 0; i < 4; i++)
#pragma unroll
        for (int j = 0; j < 4; j++) accS[i][j] = (f32x4){0.f, 0.f, 0.f, 0.f};

    const int srow = lane >> 2;
    const int sk   = (lane & 3) * 8;
    const int fr = lane & 15, fk = (lane >> 4) * 8;

    for (int k0 = 0; k0 < D_; k0 += 32) {
#pragma unroll
        for (int it = 0; it < 2; ++it) {
            const int rb = wave * 2 + it;
            const int r  = rb * 16 + srow;
            __builtin_amdgcn_global_load_lds(
                (const __attribute__((address_space(1))) unsigned int*)
                    (P + (size_t)r * D_ + k0 + sk),
                (__attribute__((address_space(3))) unsigned int*)(Ks + rb * 512),
                16, 0, 0);
            __builtin_amdgcn_global_load_lds(
                (const __attribute__((address_space(1))) unsigned int*)
                    (X + (size_t)r * D_ + k0 + sk),
                (__attribute__((address_space(3))) unsigned int*)(Qs + rb * 512),
                16, 0, 0);
        }
        __syncthreads();

        frag8 af[4], bff[4];
#pragma unroll
        for (int t = 0; t < 4; ++t)
            af[t] = *(const frag8*)&Ks[(wm + t * 16 + fr) * 32 + fk];
#pragma unroll
        for (int t = 0; t < 4; ++t)
            bff[t] = *(const frag8*)&Qs[(wn + t * 16 + fr) * 32 + fk];
#pragma unroll
        for (int i = 0; i < 4; i++)
#pragma unroll
            for (int j = 0; j < 4; j++)
                accS[i][j] = __builtin_amdgcn_mfma_f32_16x16x32_bf16(
                    af[i], bff[j], accS[i][j], 0, 0, 0);
        __syncthreads();
    }

    // epilogue: S += u[i]+v[j]; p = exp(S*scale); pair with G; reduce over q
    const float scale = 0.03125f;   // 1/sqrt(1024)
    const int col   = lane & 15;
    const int rbase = (lane >> 4) * 4;
    const unsigned short* Gt = gb + ((size_t)b * T_ + i0) * T_ + j0;
    const float* ub = u + (size_t)b * T_ + i0;
    const float* vb = v + (size_t)b * T_ + j0;

    float vval[4];
#pragma unroll
    for (int j = 0; j < 4; j++) vval[j] = vb[wn + j * 16 + col];
    float uval[4][4];
#pragma unroll
    for (int i = 0; i < 4; i++)
#pragma unroll
        for (int r = 0; r < 4; r++) uval[i][r] = ub[wm + i * 16 + rbase + r];

    float l_part[4][4], A_part[4][4];
#pragma unroll
    for (int i = 0; i < 4; i++)
#pragma unroll
        for (int r = 0; r < 4; r++) { l_part[i][r] = 0.f; A_part[i][r] = 0.f; }

#pragma unroll
    for (int i = 0; i < 4; i++)
#pragma unroll
        for (int j = 0; j < 4; j++) {
            const int gq = wn + j * 16 + col;
#pragma unroll
            for (int r = 0; r < 4; r++) {
                const int gi = wm + i * 16 + rbase + r;
                float p = __expf((accS[i][j][r] + uval[i][r] + vval[j]) * scale);
                float g = bf2f(Gt[(size_t)gi * T_ + gq]);
                l_part[i][r] += p;
                A_part[i][r] += p * g;
            }
        }

#pragma unroll
    for (int m = 1; m < 16; m <<= 1) {
#pragma unroll
        for (int i = 0; i < 4; i++)
#pragma unroll
            for (int r = 0; r < 4; r++) {
                l_part[i][r] += __shfl_xor(l_part[i][r], m);
                A_part[i][r] += __shfl_xor(A_part[i][r], m);
            }
    }

    if ((lane & 15) == 0) {
        const int half = wave & 1;     // wn half: cols 0..63 vs 64..127
        const size_t base =
            ((((size_t)b * 8 + i0b) * 8 + j0b) * 2 + half) * 128;
        float* lrow = lpart + base;
        float* Arow = Apart + base;
#pragma unroll
        for (int i = 0; i < 4; i++)
#pragma unroll
            for (int r = 0; r < 4; r++) {
                int row = wm + i * 16 + rbase + r;
                lrow[row] = l_part[i][r];
                Arow[row] = A_part[i][r];
            }
    }
}

// ---------------------------------------------------------------------------
// K5: finalize — out[b] = bfc + sum_i (sum_t Apart)/(sum_t lpart).
// Fixed summation order -> bit-deterministic.  grid (16) block 256.
// ---------------------------------------------------------------------------
__global__ __launch_bounds__(256)
void finalize(const float* __restrict__ lpart, const float* __restrict__ Apart,
              const float* __restrict__ bfc, float* __restrict__ out) {
    const int b = blockIdx.x;
    const int tid = threadIdx.x, lane = tid & 63, wave = tid >> 6;
    float s = 0.f;
#pragma unroll
    for (int p = 0; p < 4; ++p) {
        const int rg = tid + p * 256;          // 0..1023 (row index within b)
        const int i0b = rg >> 7, row = rg & 127;
        const size_t base = ((size_t)b * 8 + i0b) * 2048 + row;
        float lsum = 0.f, Asum = 0.f;
#pragma unroll
        for (int t = 0; t < 16; ++t) {         // j0b*2 + half, fixed order
            lsum += lpart[base + (size_t)t * 128];
            Asum += Apart[base + (size_t)t * 128];
        }
        s += Asum / lsum;
    }
#pragma unroll
    for (int off = 32; off; off >>= 1) s += __shfl_down(s, off);
    __shared__ float ws_[4];
    if (lane == 0) ws_[wave] = s;
    __syncthreads();
    if (tid == 0) out[b] = ws_[0] + ws_[1] + ws_[2] + ws_[3] + bfc[0];
}

extern "C" void kernel_launch(void* const* d_in, const int* in_sizes, int n_in,
                              void* d_out, int out_size, void* d_ws, size_t ws_size,
                              hipStream_t stream) {
    const float* x   = (const float*)d_in[0];
    const float* Wq  = (const float*)d_in[1];
    const float* bq  = (const float*)d_in[2];
    const float* Wk  = (const float*)d_in[3];
    const float* bk  = (const float*)d_in[4];
    const float* Wv  = (const float*)d_in[5];
    const float* bv  = (const float*)d_in[6];
    const float* Wfc = (const float*)d_in[7];
    const float* bfc = (const float*)d_in[8];
    float* out = (float*)d_out;

    // workspace layout (~110.4 MB), every byte written before read each call:
    char* ws = (char*)d_ws;
    unsigned short* xb    = (unsigned short*)ws;                   // 32 MB
    unsigned short* wqb   = xb   + (size_t)B_ * T_ * D_;           // 2 MB
    unsigned short* wkb   = wqb  + (size_t)D_ * D_;                // 2 MB
    unsigned short* wvb   = wkb  + (size_t)D_ * D_;                // 2 MB
    unsigned short* wfcb  = wvb  + (size_t)D_ * D_;                // 2 MB
    unsigned short* ntb   = wfcb + (size_t)D_ * D_;                // 2 MB
    unsigned short* mb    = ntb  + (size_t)D_ * D_;                // 2 MB
    unsigned short* pb    = mb   + (size_t)D_ * D_;                // 32 MB
    unsigned short* gbuf  = pb   + (size_t)B_ * T_ * D_;           // 32 MB
    float*          w1    = (float*)(gbuf + (size_t)B_ * T_ * T_); // 4 KB
    float*          w2    = w1 + D_;                               // 4 KB
    float*          cvec  = w2 + D_;                               // 4 KB
    float*          bkbq  = cvec + D_;                             // 16 B
    float*          u     = bkbq + 4;                              // 64 KB
    float*          v     = u + (size_t)B_ * T_;                   // 64 KB
    float*          lpart = v + (size_t)B_ * T_;                   // 1 MB (16*8*8*2*128)
    float*          Apart = lpart + (size_t)B_ * 8 * 8 * 2 * 128;  // 1 MB

    cvt_x     <<<dim3(16384),     256, 0, stream>>>(x, xb);
    cvt_w4    <<<dim3(4096),      256, 0, stream>>>(Wq, Wk, Wv, Wfc, wqb, wkb, wvb, wfcb);
    wvec      <<<dim3(256, 4),    256, 0, stream>>>(Wq, Wk, Wfc, bq, bk, bv, w1, w2, cvec, bkbq);
    small_gemm<<<dim3(8, 8, 2),   256, 0, stream>>>(wqb, wkb, wfcb, wvb, ntb, mb);
    uv_kernel <<<dim3(4096),      256, 0, stream>>>(xb, w1, w2, bkbq, u, v);
    pg_gemm   <<<dim3(8, 128, 2), 256, 0, stream>>>(xb, ntb, mb, cvec, pb, gbuf);
    score_attn<<<dim3(8, 8, 16),  256, 0, stream>>>(pb, xb, gbuf, u, v, lpart, Apart);
    finalize  <<<dim3(B_),        256, 0, stream>>>(lpart, Apart, bfc, out);
}

// Round 8
// 318.234 us; speedup vs baseline: 1.3859x; 1.0009x over previous
//
#include <hip/hip_runtime.h>
#include <hip/hip_bf16.h>

// Problem constants
#define B_ 16
#define T_ 1024
#define D_ 1024

using frag8  = __attribute__((ext_vector_type(8))) short;   // 8 bf16 (4 VGPRs)
using f32x4  = __attribute__((ext_vector_type(4))) float;   // 4 fp32 acc
using u16x8  = __attribute__((ext_vector_type(8))) unsigned short; // 16B chunk

__device__ inline unsigned short f2bf(float f) {
    union { float f; unsigned u; } v; v.f = f;
    unsigned r = v.u + 0x7FFF + ((v.u >> 16) & 1);   // round-nearest-even
    return (unsigned short)(r >> 16);
}
__device__ inline float bf2f(unsigned short u) {
    union { unsigned u; float f; } v; v.u = ((unsigned)u) << 16;
    return v.f;
}

// ---------------------------------------------------------------------------
// K0a: plain-cast Wq/Wk/Wv/Wfc fp32 -> bf16 (no transpose; all used k-major).
// grid 4096: w = bx>>10 selects the weight.
// ---------------------------------------------------------------------------
__global__ __launch_bounds__(256)
void cvt_w4(const float* __restrict__ Wq, const float* __restrict__ Wk,
            const float* __restrict__ Wv, const float* __restrict__ Wfc,
            unsigned short* __restrict__ wqb, unsigned short* __restrict__ wkb,
            unsigned short* __restrict__ wvb, unsigned short* __restrict__ wfcb) {
    const int w = blockIdx.x >> 10;
    const float* src = (w == 0) ? Wq : (w == 1) ? Wk : (w == 2) ? Wv : Wfc;
    unsigned short* dst = (w == 0) ? wqb : (w == 1) ? wkb : (w == 2) ? wvb : wfcb;
    int i = (blockIdx.x & 1023) * 256 + threadIdx.x;
    float4 v = ((const float4*)src)[i];
    ushort4 o;
    o.x = f2bf(v.x); o.y = f2bf(v.y); o.z = f2bf(v.z); o.w = f2bf(v.w);
    ((ushort4*)dst)[i] = o;
}

// ---------------------------------------------------------------------------
// K0b: weight-bias vectors (fp32, exact):
//  y=0: w1[e] = Wk[e]·bq     y=1: w2[e] = Wq[e]·bk
//  y=2: c[q]  = Wfc_row(q)·bv   y=3 (block 0 only): bkbq = bk·bq
// grid (256, 4), block 256 (4 waves, 1 row/wave).
// ---------------------------------------------------------------------------
__global__ __launch_bounds__(256)
void wvec(const float* __restrict__ Wq, const float* __restrict__ Wk,
          const float* __restrict__ Wfc,
          const float* __restrict__ bq, const float* __restrict__ bk,
          const float* __restrict__ bv,
          float* __restrict__ w1, float* __restrict__ w2,
          float* __restrict__ cvec, float* __restrict__ bkbq) {
    const int y = blockIdx.y;
    const int tid = threadIdx.x, lane = tid & 63, wave = tid >> 6;
    if (y == 3) {
        if (blockIdx.x != 0) return;
        float s = 0.f;
#pragma unroll
        for (int p = 0; p < 4; ++p) { int i = tid + p * 256; s += bk[i] * bq[i]; }
#pragma unroll
        for (int off = 32; off; off >>= 1) s += __shfl_down(s, off);
        __shared__ float sm[4];
        if (lane == 0) sm[wave] = s;
        __syncthreads();
        if (tid == 0) bkbq[0] = sm[0] + sm[1] + sm[2] + sm[3];
        return;
    }
    const float* Wsrc; const float* bvv; float* outp;
    if (y == 0)      { Wsrc = Wk;  bvv = bq; outp = w1; }
    else if (y == 1) { Wsrc = Wq;  bvv = bk; outp = w2; }
    else             { Wsrc = Wfc; bvv = bv; outp = cvec; }
    const int row = blockIdx.x * 4 + wave;
    const float* r = Wsrc + (size_t)row * D_;
    float s = 0.f;
#pragma unroll
    for (int it = 0; it < 4; ++it) {
        float4 a = *(const float4*)&r[it * 256 + lane * 4];
        float4 b = *(const float4*)&bvv[it * 256 + lane * 4];
        s += a.x * b.x + a.y * b.y + a.z * b.z + a.w * b.w;
    }
#pragma unroll
    for (int off = 32; off; off >>= 1) s += __shfl_down(s, off);
    if (lane == 0) outp[row] = s;
}

// ---------------------------------------------------------------------------
// K0c: FUSED x fp32 -> bf16 cast + u/v row dots (single pass over x).
//  xb[row] = bf16(x[row]);  u[row] = x[row]·w1;  v[row] = x[row]·w2 + bkbq.
// grid 4096, block 256 (4 waves, 1 row/wave); coalesced float4/ushort4.
// ---------------------------------------------------------------------------
__global__ __launch_bounds__(256)
void cvt_x_uv(const float* __restrict__ x, unsigned short* __restrict__ xb,
              const float* __restrict__ w1, const float* __restrict__ w2,
              const float* __restrict__ bkbq,
              float* __restrict__ u, float* __restrict__ v) {
    __shared__ float s1[1024], s2[1024];
    const int tid = threadIdx.x, lane = tid & 63, wave = tid >> 6;
#pragma unroll
    for (int p = 0; p < 4; ++p) {
        int i = tid + p * 256;
        s1[i] = w1[i]; s2[i] = w2[i];
    }
    __syncthreads();
    const int row = blockIdx.x * 4 + wave;
    const float* xr = x + (size_t)row * D_;
    unsigned short* xo = xb + (size_t)row * D_;
    float du = 0.f, dv = 0.f;
#pragma unroll
    for (int k = 0; k < 4; ++k) {
        const int e0 = k * 256 + lane * 4;
        float4 a = *(const float4*)&xr[e0];
        ushort4 o;
        o.x = f2bf(a.x); o.y = f2bf(a.y); o.z = f2bf(a.z); o.w = f2bf(a.w);
        *(ushort4*)&xo[e0] = o;
        du += a.x * s1[e0] + a.y * s1[e0 + 1] + a.z * s1[e0 + 2] + a.w * s1[e0 + 3];
        dv += a.x * s2[e0] + a.y * s2[e0 + 1] + a.z * s2[e0 + 2] + a.w * s2[e0 + 3];
    }
#pragma unroll
    for (int off = 32; off; off >>= 1) {
        du += __shfl_down(du, off);
        dv += __shfl_down(dv, off);
    }
    if (lane == 0) { u[row] = du; v[row] = dv + bkbq[0]; }
}

// ---------------------------------------------------------------------------
// K1: small weight-product GEMMs (m97-style), 1024x1024x1024 each:
//  z=0: NT[f][e] = sum_d Wq[f][d]·Wk[e][d]   -> ntb
//  z=1: M [q][e] = sum_d Wfc[q][d]·Wv[e][d]  -> mb
// grid (8, 8, 2) block 256.
// ---------------------------------------------------------------------------
__global__ __launch_bounds__(256)
void small_gemm(const unsigned short* __restrict__ wqb,
                const unsigned short* __restrict__ wkb,
                const unsigned short* __restrict__ wfcb,
                const unsigned short* __restrict__ wvb,
                unsigned short* __restrict__ ntb,
                unsigned short* __restrict__ mb) {
    __shared__ __align__(16) unsigned short As[128 * 32];
    __shared__ __align__(16) unsigned short Bs[128 * 32];

    const int z  = blockIdx.z;
    const int n0 = blockIdx.x * 128;
    const int m0 = blockIdx.y * 128;
    const unsigned short* A  = z ? wfcb : wqb;
    const unsigned short* Bm = z ? wvb  : wkb;
    unsigned short* out = z ? mb : ntb;

    const int tid = threadIdx.x, lane = tid & 63, wave = tid >> 6;
    const int wm = (wave >> 1) * 64, wn = (wave & 1) * 64;

    f32x4 acc[4][4];
#pragma unroll
    for (int i = 0; i < 4; i++)
#pragma unroll
        for (int j = 0; j < 4; j++) acc[i][j] = (f32x4){0.f, 0.f, 0.f, 0.f};

    const int srow = lane >> 2;
    const int sk   = (lane & 3) * 8;
    const int fr = lane & 15, fk = (lane >> 4) * 8;

    for (int k0 = 0; k0 < D_; k0 += 32) {
#pragma unroll
        for (int it = 0; it < 2; ++it) {
            const int rb = wave * 2 + it;
            const int r  = rb * 16 + srow;
            __builtin_amdgcn_global_load_lds(
                (const __attribute__((address_space(1))) unsigned int*)
                    (A + (size_t)(m0 + r) * D_ + k0 + sk),
                (__attribute__((address_space(3))) unsigned int*)(As + rb * 512),
                16, 0, 0);
            __builtin_amdgcn_global_load_lds(
                (const __attribute__((address_space(1))) unsigned int*)
                    (Bm + (size_t)(n0 + r) * D_ + k0 + sk),
                (__attribute__((address_space(3))) unsigned int*)(Bs + rb * 512),
                16, 0, 0);
        }
        __syncthreads();

        frag8 af[4], bff[4];
#pragma unroll
        for (int t = 0; t < 4; ++t)
            af[t] = *(const frag8*)&As[(wm + t * 16 + fr) * 32 + fk];
#pragma unroll
        for (int t = 0; t < 4; ++t)
            bff[t] = *(const frag8*)&Bs[(wn + t * 16 + fr) * 32 + fk];
#pragma unroll
        for (int i = 0; i < 4; i++)
#pragma unroll
            for (int j = 0; j < 4; j++)
                acc[i][j] = __builtin_amdgcn_mfma_f32_16x16x32_bf16(
                    af[i], bff[j], acc[i][j], 0, 0, 0);
        __syncthreads();
    }

    const int col   = lane & 15;
    const int rbase = (lane >> 4) * 4;
#pragma unroll
    for (int i = 0; i < 4; i++) {
#pragma unroll
        for (int j = 0; j < 4; j++) {
            int gn = n0 + wn + j * 16 + col;
#pragma unroll
            for (int r = 0; r < 4; r++) {
                int gm = m0 + wm + i * 16 + rbase + r;
                out[(size_t)gm * D_ + gn] = f2bf(acc[i][j][r]);
            }
        }
    }
}

// ---------------------------------------------------------------------------
// K2: fused P/G GEMM.  Both share A = xb (M=16384, K=1024, N=1024):
//  z=0: P[i][f] = sum_e x[i][e]·NT[f][e]           -> pb (row-major bf16)
//  z=1: G[i][q] = sum_e x[i][e]·M[q][e] + c[q]     -> gbuf SWIZZLED:
//       per 128x128 tile (tile = mblk*8 + nblk), per-thread contiguous
//       64-elem fragment: gbuf[tile*16384 + chunk*2048 + tid*8 + e],
//       flat f = chunk*8+e maps (i=f>>4, j=(f>>2)&3, r=f&3) of acc —
//       exactly what score_attn's lane (same wave/lane layout) consumes.
// XCD swizzle: each XCD owns 16 m-blocks (4 MB of x, L2-resident).
// grid (8, 128, 2), linear = x + 8y + 1024z.
// ---------------------------------------------------------------------------
__global__ __launch_bounds__(256)
void pg_gemm(const unsigned short* __restrict__ xb,
             const unsigned short* __restrict__ ntb,
             const unsigned short* __restrict__ mb,
             const float* __restrict__ cvec,
             unsigned short* __restrict__ pb,
             unsigned short* __restrict__ gbuf) {
    __shared__ __align__(16) unsigned short As[128 * 32];
    __shared__ __align__(16) unsigned short Bs[128 * 32];

    const int l    = blockIdx.x + 8 * blockIdx.y + 1024 * blockIdx.z;
    const int xcd  = l & 7;
    const int idx  = l >> 3;            // 0..255
    const int mblk = xcd * 16 + (idx & 15);
    const int rest = idx >> 4;          // 0..15
    const int z    = rest >> 3;
    const int nblk = rest & 7;
    const int n0   = nblk * 128;
    const int m0   = mblk * 128;

    const unsigned short* Bm = z ? mb : ntb;

    const int tid = threadIdx.x, lane = tid & 63, wave = tid >> 6;
    const int wm = (wave >> 1) * 64, wn = (wave & 1) * 64;

    f32x4 acc[4][4];
#pragma unroll
    for (int i = 0; i < 4; i++)
#pragma unroll
        for (int j = 0; j < 4; j++) acc[i][j] = (f32x4){0.f, 0.f, 0.f, 0.f};

    const int srow = lane >> 2;
    const int sk   = (lane & 3) * 8;
    const int fr = lane & 15, fk = (lane >> 4) * 8;

    for (int k0 = 0; k0 < D_; k0 += 32) {
#pragma unroll
        for (int it = 0; it < 2; ++it) {
            const int rb = wave * 2 + it;
            const int r  = rb * 16 + srow;
            __builtin_amdgcn_global_load_lds(
                (const __attribute__((address_space(1))) unsigned int*)
                    (xb + (size_t)(m0 + r) * D_ + k0 + sk),
                (__attribute__((address_space(3))) unsigned int*)(As + rb * 512),
                16, 0, 0);
            __builtin_amdgcn_global_load_lds(
                (const __attribute__((address_space(1))) unsigned int*)
                    (Bm + (size_t)(n0 + r) * D_ + k0 + sk),
                (__attribute__((address_space(3))) unsigned int*)(Bs + rb * 512),
                16, 0, 0);
        }
        __syncthreads();

        frag8 af[4], bff[4];
#pragma unroll
        for (int t = 0; t < 4; ++t)
            af[t] = *(const frag8*)&As[(wm + t * 16 + fr) * 32 + fk];
#pragma unroll
        for (int t = 0; t < 4; ++t)
            bff[t] = *(const frag8*)&Bs[(wn + t * 16 + fr) * 32 + fk];
#pragma unroll
        for (int i = 0; i < 4; i++)
#pragma unroll
            for (int j = 0; j < 4; j++)
                acc[i][j] = __builtin_amdgcn_mfma_f32_16x16x32_bf16(
                    af[i], bff[j], acc[i][j], 0, 0, 0);
        __syncthreads();
    }

    const int col   = lane & 15;
    const int rbase = (lane >> 4) * 4;
    if (z == 0) {
        // P: row-major store (consumed via global_load_lds row staging)
#pragma unroll
        for (int i = 0; i < 4; i++) {
#pragma unroll
            for (int j = 0; j < 4; j++) {
                int gn = n0 + wn + j * 16 + col;
#pragma unroll
                for (int r = 0; r < 4; r++) {
                    int gm = m0 + wm + i * 16 + rbase + r;
                    pb[(size_t)gm * D_ + gn] = f2bf(acc[i][j][r]);
                }
            }
        }
    } else {
        // G: fragment-swizzled store, 8 coalesced 16B chunks per thread
        float bb[4];
#pragma unroll
        for (int j = 0; j < 4; j++) bb[j] = cvec[n0 + wn + j * 16 + col];
        unsigned short* base = gbuf + ((size_t)(mblk * 8 + nblk) << 14) + tid * 8;
#pragma unroll
        for (int c = 0; c < 8; ++c) {
            const int i = c >> 1;
            u16x8 o;
#pragma unroll
            for (int e = 0; e < 8; ++e) {
                const int f  = c * 8 + e;
                const int jj = (f >> 2) & 3;
                const int r  = f & 3;
                o[e] = f2bf(acc[i][jj][r] + bb[jj]);
            }
            *(u16x8*)(base + (size_t)c * 2048) = o;
        }
    }
}

// ---------------------------------------------------------------------------
// K3: score + exp + G-weighted row reduction — DETERMINISTIC (no atomics).
// S[i][j] = sum_f P[b·T+i][f]·x[b·T+j][f] + u[b·T+i] + v[b·T+j]
// p = exp(S*scale).  G read from the fragment-swizzled gbuf (8 coalesced
// b128 loads/lane).  Each block writes per-column-half row partials:
// lpart/Apart[(((b*8+i0b)*8+j0b)*2+half)*128 + row] — every slot written
// exactly once; finalize sums in fixed order.  grid (8,8,16) block 256.
// ---------------------------------------------------------------------------
__global__ __launch_bounds__(256)
void score_attn(const unsigned short* __restrict__ pbuf,
                const unsigned short* __restrict__ xb,
                const unsigned short* __restrict__ gb,
                const float* __restrict__ u, const float* __restrict__ v,
                float* __restrict__ lpart, float* __restrict__ Apart) {
    __shared__ __align__(16) unsigned short Ks[128 * 32];
    __shared__ __align__(16) unsigned short Qs[128 * 32];

    const int l   = blockIdx.x + 8 * blockIdx.y + 64 * blockIdx.z;
    const int xcd = l & 7;
    const int uix = l >> 3;            // 0..127
    const int i0b = uix >> 4;          // 0..7  (i0 outer)
    const int mid = uix & 15;
    const int b   = xcd * 2 + (mid >> 3);
    const int j0b = mid & 7;           // j0 inner
    const int i0 = i0b * 128, j0 = j0b * 128;

    const unsigned short* P = pbuf + ((size_t)b * T_ + i0) * D_;
    const unsigned short* X = xb   + ((size_t)b * T_ + j0) * D_;

    const int tid = threadIdx.x, lane = tid & 63, wave = tid >> 6;
    const int wm = (wave >> 1) * 64, wn = (wave & 1) * 64;

    f32x4 accS[4][4];
#pragma unroll
    for (int i = 0; i < 4; i++)
#pragma unroll
        for (int j = 0; j < 4; j++) accS[i][j] = (f32x4){0.f, 0.f, 0.f, 0.f};

    const int srow = lane >> 2;
    const int sk   = (lane & 3) * 8;
    const int fr = lane & 15, fk = (lane >> 4) * 8;

    for (int k0 = 0; k0 < D_; k0 += 32) {
#pragma unroll
        for (int it = 0; it < 2; ++it) {
            const int rb = wave * 2 + it;
            const int r  = rb * 16 + srow;
            __builtin_amdgcn_global_load_lds(
                (const __attribute__((address_space(1))) unsigned int*)
                    (P + (size_t)r * D_ + k0 + sk),
                (__attribute__((address_space(3))) unsigned int*)(Ks + rb * 512),
                16, 0, 0);
            __builtin_amdgcn_global_load_lds(
                (const __attribute__((address_space(1))) unsigned int*)
                    (X + (size_t)r * D_ + k0 + sk),
                (__attribute__((address_space(3))) unsigned int*)(Qs + rb * 512),
                16, 0, 0);
        }
        __syncthreads();

        frag8 af[4], bff[4];
#pragma unroll
        for (int t = 0; t < 4; ++t)
            af[t] = *(const frag8*)&Ks[(wm + t * 16 + fr) * 32 + fk];
#pragma unroll
        for (int t = 0; t < 4; ++t)
            bff[t] = *(const frag8*)&Qs[(wn + t * 16 + fr) * 32 + fk];
#pragma unroll
        for (int i = 0; i < 4; i++)
#pragma unroll
            for (int j = 0; j < 4; j++)
                accS[i][j] = __builtin_amdgcn_mfma_f32_16x16x32_bf16(
                    af[i], bff[j], accS[i][j], 0, 0, 0);
        __syncthreads();
    }

    // epilogue: S += u[i]+v[j]; p = exp(S*scale); pair with swizzled G
    const float scale = 0.03125f;   // 1/sqrt(1024)
    const int col   = lane & 15;
    const int rbase = (lane >> 4) * 4;
    const float* ub = u + (size_t)b * T_ + i0;
    const float* vb = v + (size_t)b * T_ + j0;

    float vval[4];
#pragma unroll
    for (int j = 0; j < 4; j++) vval[j] = vb[wn + j * 16 + col];
    float uval[4][4];
#pragma unroll
    for (int i = 0; i < 4; i++)
#pragma unroll
        for (int r = 0; r < 4; r++) uval[i][r] = ub[wm + i * 16 + rbase + r];

    float l_part[4][4], A_part[4][4];
#pragma unroll
    for (int i = 0; i < 4; i++)
#pragma unroll
        for (int r = 0; r < 4; r++) { l_part[i][r] = 0.f; A_part[i][r] = 0.f; }

    const unsigned short* Gt =
        gb + (((size_t)(b * 8 + i0b) * 8 + j0b) << 14) + tid * 8;
#pragma unroll
    for (int c = 0; c < 8; ++c) {
        u16x8 gv = *(const u16x8*)(Gt + (size_t)c * 2048);
        const int i = c >> 1;
#pragma unroll
        for (int e = 0; e < 8; ++e) {
            const int f  = c * 8 + e;
            const int jj = (f >> 2) & 3;
            const int r  = f & 3;
            float p = __expf((accS[i][jj][r] + uval[i][r] + vval[jj]) * scale);
            float g = bf2f(gv[e]);
            l_part[i][r] += p;
            A_part[i][r] += p * g;
        }
    }

#pragma unroll
    for (int m = 1; m < 16; m <<= 1) {
#pragma unroll
        for (int i = 0; i < 4; i++)
#pragma unroll
            for (int r = 0; r < 4; r++) {
                l_part[i][r] += __shfl_xor(l_part[i][r], m);
                A_part[i][r] += __shfl_xor(A_part[i][r], m);
            }
    }

    if ((lane & 15) == 0) {
        const int half = wave & 1;     // wn half: cols 0..63 vs 64..127
        const size_t base =
            ((((size_t)b * 8 + i0b) * 8 + j0b) * 2 + half) * 128;
        float* lrow = lpart + base;
        float* Arow = Apart + base;
#pragma unroll
        for (int i = 0; i < 4; i++)
#pragma unroll
            for (int r = 0; r < 4; r++) {
                int row = wm + i * 16 + rbase + r;
                lrow[row] = l_part[i][r];
                Arow[row] = A_part[i][r];
            }
    }
}

// ---------------------------------------------------------------------------
// K4: finalize — out[b] = bfc + sum_i (sum_t Apart)/(sum_t lpart).
// Fixed summation order -> bit-deterministic.  grid (16) block 256.
// ---------------------------------------------------------------------------
__global__ __launch_bounds__(256)
void finalize(const float* __restrict__ lpart, const float* __restrict__ Apart,
              const float* __restrict__ bfc, float* __restrict__ out) {
    const int b = blockIdx.x;
    const int tid = threadIdx.x, lane = tid & 63, wave = tid >> 6;
    float s = 0.f;
#pragma unroll
    for (int p = 0; p < 4; ++p) {
        const int rg = tid + p * 256;          // 0..1023 (row index within b)
        const int i0b = rg >> 7, row = rg & 127;
        const size_t base = ((size_t)b * 8 + i0b) * 2048 + row;
        float lsum = 0.f, Asum = 0.f;
#pragma unroll
        for (int t = 0; t < 16; ++t) {         // j0b*2 + half, fixed order
            lsum += lpart[base + (size_t)t * 128];
            Asum += Apart[base + (size_t)t * 128];
        }
        s += Asum / lsum;
    }
#pragma unroll
    for (int off = 32; off; off >>= 1) s += __shfl_down(s, off);
    __shared__ float ws_[4];
    if (lane == 0) ws_[wave] = s;
    __syncthreads();
    if (tid == 0) out[b] = ws_[0] + ws_[1] + ws_[2] + ws_[3] + bfc[0];
}

extern "C" void kernel_launch(void* const* d_in, const int* in_sizes, int n_in,
                              void* d_out, int out_size, void* d_ws, size_t ws_size,
                              hipStream_t stream) {
    const float* x   = (const float*)d_in[0];
    const float* Wq  = (const float*)d_in[1];
    const float* bq  = (const float*)d_in[2];
    const float* Wk  = (const float*)d_in[3];
    const float* bk  = (const float*)d_in[4];
    const float* Wv  = (const float*)d_in[5];
    const float* bv  = (const float*)d_in[6];
    const float* Wfc = (const float*)d_in[7];
    const float* bfc = (const float*)d_in[8];
    float* out = (float*)d_out;

    // workspace layout (~110.4 MB), every byte written before read each call:
    char* ws = (char*)d_ws;
    unsigned short* xb    = (unsigned short*)ws;                   // 32 MB
    unsigned short* wqb   = xb   + (size_t)B_ * T_ * D_;           // 2 MB
    unsigned short* wkb   = wqb  + (size_t)D_ * D_;                // 2 MB
    unsigned short* wvb   = wkb  + (size_t)D_ * D_;                // 2 MB
    unsigned short* wfcb  = wvb  + (size_t)D_ * D_;                // 2 MB
    unsigned short* ntb   = wfcb + (size_t)D_ * D_;                // 2 MB
    unsigned short* mb    = ntb  + (size_t)D_ * D_;                // 2 MB
    unsigned short* pb    = mb   + (size_t)D_ * D_;                // 32 MB
    unsigned short* gbuf  = pb   + (size_t)B_ * T_ * D_;           // 32 MB
    float*          w1    = (float*)(gbuf + (size_t)B_ * T_ * T_); // 4 KB
    float*          w2    = w1 + D_;                               // 4 KB
    float*          cvec  = w2 + D_;                               // 4 KB
    float*          bkbq  = cvec + D_;                             // 16 B
    float*          u     = bkbq + 4;                              // 64 KB
    float*          v     = u + (size_t)B_ * T_;                   // 64 KB
    float*          lpart = v + (size_t)B_ * T_;                   // 1 MB
    float*          Apart = lpart + (size_t)B_ * 8 * 8 * 2 * 128;  // 1 MB

    cvt_w4    <<<dim3(4096),      256, 0, stream>>>(Wq, Wk, Wv, Wfc, wqb, wkb, wvb, wfcb);
    wvec      <<<dim3(256, 4),    256, 0, stream>>>(Wq, Wk, Wfc, bq, bk, bv, w1, w2, cvec, bkbq);
    cvt_x_uv  <<<dim3(4096),      256, 0, stream>>>(x, xb, w1, w2, bkbq, u, v);
    small_gemm<<<dim3(8, 8, 2),   256, 0, stream>>>(wqb, wkb, wfcb, wvb, ntb, mb);
    pg_gemm   <<<dim3(8, 128, 2), 256, 0, stream>>>(xb, ntb, mb, cvec, pb, gbuf);
    score_attn<<<dim3(8, 8, 16),  256, 0, stream>>>(pb, xb, gbuf, u, v, lpart, Apart);
    finalize  <<<dim3(B_),        256, 0, stream>>>(lpart, Apart, bfc, out);
}